// Round 3
// baseline (781.738 us; speedup 1.0000x reference)
//
#include <hip/hip_runtime.h>
#include <stdint.h>

#define N_NODES 100000
#define F_DIM   500
#define C_DIM   40
#define H_DIM   256
#define HX_DIM  64
#define O_DIM   320   // H + HX
#define E_NUM   1600000

typedef unsigned short u16;
typedef unsigned int   u32;
typedef __attribute__((ext_vector_type(4))) u16    u16x4;
typedef __attribute__((ext_vector_type(8))) u16    u16x8;
typedef __attribute__((ext_vector_type(4))) float  f32x4;
typedef __attribute__((ext_vector_type(8))) short  bf16x8;  // MFMA A/B frag

__device__ __forceinline__ float bf2f(u16 v) {
  u32 u = ((u32)v) << 16;
  return __builtin_bit_cast(float, u);
}
__device__ __forceinline__ u16 f2bf(float f) {   // round-to-nearest-even
  u32 x = __builtin_bit_cast(u32, f);
  x += 0x7fffu + ((x >> 16) & 1u);
  return (u16)(x >> 16);
}

// ---------------- Kernel 0: train_mask encoding detector ----------------
__global__ __launch_bounds__(256) void k_detect(const u32* __restrict__ tm, int* __restrict__ flag)
{
  __shared__ int s;
  if (threadIdx.x == 0) s = 0;
  __syncthreads();
  int local = 0;
  for (int i = threadIdx.x; i < N_NODES / 4; i += 256) {
    if (tm[i] > 1u) local = 1;
  }
  if (local) s = 1;             // benign race: all writers store 1
  __syncthreads();
  if (threadIdx.x == 0) *flag = s;
}

// ---------------- Kernel 1: [h|xe] = relu(x @ [fc1_w;xenc_w]^T + b) ----------------
#define BM  128
#define BN  320
#define LDX 40

__device__ __forceinline__ void stage_load(
    int tid, int kc, long rowbase,
    const float* __restrict__ x, const float* __restrict__ fc1w, const float* __restrict__ xencw,
    f32x4 st[7])
{
  #pragma unroll
  for (int j = 0; j < 7; ++j) {
    const int g  = tid + 512 * j;            // 3584 groups: 1024 A + 2560 B
    const int k0 = kc * 32 + (g & 7) * 4;
    const bool kval = (k0 + 4 <= F_DIM);     // F%4==0: float4 fully valid or fully OOB
    f32x4 v = (f32x4){0.f, 0.f, 0.f, 0.f};
    if (g < 1024) {
      const long rr = rowbase + (g >> 3);
      if (kval && rr < N_NODES) v = *(const f32x4*)(x + rr * F_DIM + k0);
    } else {
      const int o = (g - 1024) >> 3;
      if (kval) {
        const float* p = (o < H_DIM) ? (fc1w + (long)o * F_DIM + k0)
                                     : (xencw + (long)(o - H_DIM) * F_DIM + k0);
        v = *(const f32x4*)p;
      }
    }
    st[j] = v;
  }
}

__device__ __forceinline__ void stage_store(int tid, u16* __restrict__ sA, u16* __restrict__ sB,
                                            const f32x4 st[7])
{
  #pragma unroll
  for (int j = 0; j < 7; ++j) {
    const int g = tid + 512 * j;
    u16x4 b;
    #pragma unroll
    for (int i = 0; i < 4; ++i) b[i] = f2bf(st[j][i]);
    u16* dst;
    if (g < 1024) dst = sA + (g >> 3) * LDX + (g & 7) * 4;
    else          dst = sB + ((g - 1024) >> 3) * LDX + (g & 7) * 4;
    *(u16x4*)dst = b;
  }
}

__global__ __launch_bounds__(512) void k_gemm1(
    const float* __restrict__ x, const float* __restrict__ fc1w, const float* __restrict__ fc1b,
    const float* __restrict__ xencw, const float* __restrict__ xencb, u16* __restrict__ hout)
{
  __shared__ u16 sA[2][BM * LDX];
  __shared__ u16 sB[2][BN * LDX];
  const int tid  = threadIdx.x;
  const int lane = tid & 63;
  const int wid  = tid >> 6;
  const int wr = wid >> 2, wc = wid & 3;
  const long rowbase = (long)blockIdx.x * BM;

  f32x4 acc[4][5];
  #pragma unroll
  for (int m = 0; m < 4; ++m)
    #pragma unroll
    for (int n = 0; n < 5; ++n)
      acc[m][n] = (f32x4){0.f, 0.f, 0.f, 0.f};

  f32x4 st[7];
  stage_load(tid, 0, rowbase, x, fc1w, xencw, st);
  stage_store(tid, &sA[0][0], &sB[0][0], st);
  __syncthreads();

  for (int kc = 0; kc < 16; ++kc) {
    const int cur = kc & 1;
    if (kc < 15) stage_load(tid, kc + 1, rowbase, x, fc1w, xencw, st);

    bf16x8 a[4], b[5];
    const u16* pa = &sA[cur][(wr * 64 + (lane & 15)) * LDX + (lane >> 4) * 8];
    #pragma unroll
    for (int m = 0; m < 4; ++m) a[m] = *(const bf16x8*)(pa + m * 16 * LDX);
    const u16* pb = &sB[cur][(wc * 80 + (lane & 15)) * LDX + (lane >> 4) * 8];
    #pragma unroll
    for (int n = 0; n < 5; ++n) b[n] = *(const bf16x8*)(pb + n * 16 * LDX);

    #pragma unroll
    for (int m = 0; m < 4; ++m)
      #pragma unroll
      for (int n = 0; n < 5; ++n)
        acc[m][n] = __builtin_amdgcn_mfma_f32_16x16x32_bf16(a[m], b[n], acc[m][n], 0, 0, 0);

    if (kc < 15) stage_store(tid, &sA[cur ^ 1][0], &sB[cur ^ 1][0], st);
    __syncthreads();
  }

  // epilogue: bias + relu + bf16 store. C/D: col=lane&15, row=(lane>>4)*4+reg.
  #pragma unroll
  for (int n = 0; n < 5; ++n) {
    const int col = wc * 80 + n * 16 + (lane & 15);
    const float bias = (col < H_DIM) ? fc1b[col] : xencb[col - H_DIM];
    #pragma unroll
    for (int m = 0; m < 4; ++m) {
      const long row0 = rowbase + wr * 64 + m * 16 + ((lane >> 4) << 2);
      #pragma unroll
      for (int rg = 0; rg < 4; ++rg) {
        const long rr = row0 + rg;
        if (rr < N_NODES) {
          const float v = fmaxf(acc[m][n][rg] + bias, 0.f);
          hout[rr * O_DIM + col] = f2bf(v);
        }
      }
    }
  }
}

// ---------------- Kernel 2: LDS-staged row head ----------------
// Block = 256 threads, 64 rows. Stage hws rows coalesced into LDS (stride 328 u16:
// 164 dw === 4 mod 32 -> the 8-row x 16B compute reads tile all 32 banks, conflict-free).
// Then 4 waves x 16 rows, 8 lanes/row (cg = class group of 5). lp staged in LDS for
// coalesced writeback.
#define RH_ROWS 64
#define SH_LD   328

__global__ __launch_bounds__(256) void k_rowhead(
    const u16* __restrict__ hws, const int* __restrict__ y, const void* __restrict__ tmask,
    const float* __restrict__ fc2w, const float* __restrict__ fc2b, const float* __restrict__ pw,
    const int* __restrict__ mask_flag,
    float* __restrict__ out_lp, float* __restrict__ sq_out, float* __restrict__ sk_out)
{
  __shared__ u16   sh[RH_ROWS][SH_LD];    // 41984 B
  __shared__ float slp[RH_ROWS][C_DIM];   // 10240 B  (52224 total -> 3 blocks/CU)

  const int tid = threadIdx.x;
  const int lane = tid & 63, wid = tid >> 6;
  const int rowsub = lane >> 3, cg = lane & 7;
  const long rowbase = (long)blockIdx.x * RH_ROWS;

  // ---- stage: 64 rows x 320 u16 = 2560 16B-groups, coalesced ----
  #pragma unroll
  for (int it = 0; it < 10; ++it) {
    const int g = it * 256 + tid;          // < 2560
    const int r = g / 40, c = g - r * 40;  // c: 16B group within row
    const long rr = rowbase + r;
    u16x8 v = {0, 0, 0, 0, 0, 0, 0, 0};
    if (rr < N_NODES) v = *(const u16x8*)(hws + rr * O_DIM + c * 8);
    *(u16x8*)&sh[r][c * 8] = v;
  }
  __syncthreads();

  const bool byte_mask = (*mask_flag != 0);

  #pragma unroll
  for (int hs = 0; hs < 2; ++hs) {
    const int r = wid * 16 + hs * 8 + rowsub;   // block-local row
    const long row = rowbase + r;
    const bool rv = (row < N_NODES);

    float lg[5];
    #pragma unroll
    for (int i = 0; i < 5; ++i) lg[i] = fc2b[cg * 5 + i];

    #pragma unroll 4
    for (int h0 = 0; h0 < H_DIM; h0 += 8) {
      const u16x8 hv = *(const u16x8*)&sh[r][h0];
      float hf[8];
      #pragma unroll
      for (int i = 0; i < 8; ++i) hf[i] = bf2f(hv[i]);
      #pragma unroll
      for (int i = 0; i < 5; ++i) {
        const float* wv = fc2w + (cg * 5 + i) * H_DIM + h0;
        const f32x4 w0 = *(const f32x4*)wv;
        const f32x4 w1 = *(const f32x4*)(wv + 4);
        #pragma unroll
        for (int k = 0; k < 4; ++k) lg[i] += hf[k] * w0[k];
        #pragma unroll
        for (int k = 0; k < 4; ++k) lg[i] += hf[4 + k] * w1[k];
      }
    }

    float m = lg[0];
    #pragma unroll
    for (int i = 1; i < 5; ++i) m = fmaxf(m, lg[i]);
    #pragma unroll
    for (int off = 1; off < 8; off <<= 1) m = fmaxf(m, __shfl_xor(m, off));
    float ex[5], s = 0.f;
    #pragma unroll
    for (int i = 0; i < 5; ++i) { ex[i] = __expf(lg[i] - m); s += ex[i]; }
    #pragma unroll
    for (int off = 1; off < 8; off <<= 1) s += __shfl_xor(s, off);
    const float lse = m + __logf(s);
    const float inv = 1.f / s;

    const int yv = rv ? y[row] : 0;
    const bool tm = rv ? (byte_mask ? (((const unsigned char*)tmask)[row] != 0)
                                    : (((const int*)tmask)[row] != 0))
                       : false;
    float sq = 0.f, sk = 0.f;
    #pragma unroll
    for (int i = 0; i < 5; ++i) {
      const int c = cg * 5 + i;
      slp[r][c] = lg[i] - lse;
      const float p = tm ? (c == yv ? 1.f : 0.f) : ex[i] * inv;
      sq += p * pw[2 * HX_DIM + c];            // w_yq
      sk += p * pw[2 * HX_DIM + C_DIM + c];    // w_yk
    }
    // xe contribution: this lane covers xe[cg*8 .. cg*8+8)
    const u16x8 xv = *(const u16x8*)&sh[r][H_DIM + cg * 8];
    #pragma unroll
    for (int i = 0; i < 8; ++i) {
      const float xe = bf2f(xv[i]);
      sq += xe * pw[cg * 8 + i];               // w_xq
      sk += xe * pw[HX_DIM + cg * 8 + i];      // w_xk
    }
    #pragma unroll
    for (int off = 1; off < 8; off <<= 1) {
      sq += __shfl_xor(sq, off);
      sk += __shfl_xor(sk, off);
    }
    if (cg == 0 && rv) { sq_out[row] = sq; sk_out[row] = sk; }
  }
  __syncthreads();

  // ---- coalesced lp writeback: 2560 consecutive floats ----
  const long base = rowbase * C_DIM;
  const float* slpf = (const float*)slp;
  #pragma unroll
  for (int it = 0; it < 10; ++it) {
    const int k = it * 256 + tid;
    const long idx = base + k;
    if (idx < (long)N_NODES * C_DIM) out_lp[idx] = slpf[k];
  }
}

// ---------------- Kernel 3: edge scores ----------------
__global__ __launch_bounds__(256) void k_edges(
    const int* __restrict__ ei, const int* __restrict__ ein,
    const float* __restrict__ sq, const float* __restrict__ sk,
    const float* __restrict__ pb, float* __restrict__ out)
{
  const int e = blockIdx.x * 256 + threadIdx.x;
  if (e >= E_NUM) return;
  const float b = pb[0];
  const int a0 = ei[e],  a1 = ei[E_NUM + e];
  out[e] = sq[a0] + sk[a1] + b;
  const int c0 = ein[e], c1 = ein[E_NUM + e];
  out[E_NUM + e] = sq[c0] + sk[c1] + b;
}

extern "C" void kernel_launch(void* const* d_in, const int* in_sizes, int n_in,
                              void* d_out, int out_size, void* d_ws, size_t ws_size,
                              hipStream_t stream)
{
  const float* x     = (const float*)d_in[0];
  const int*   y     = (const int*)d_in[1];
  const void*  tm    = d_in[2];
  const int*   ei    = (const int*)d_in[3];
  const int*   ein   = (const int*)d_in[4];
  const float* fc1w  = (const float*)d_in[5];
  const float* fc1b  = (const float*)d_in[6];
  const float* fc2w  = (const float*)d_in[7];
  const float* fc2b  = (const float*)d_in[8];
  const float* xencw = (const float*)d_in[9];
  const float* xencb = (const float*)d_in[10];
  const float* pw    = (const float*)d_in[11];
  const float* pb    = (const float*)d_in[12];
  float* out = (float*)d_out;

  // workspace: h|xe (N x 320 bf16, 64 MB) | s_q (N f32) | s_k (N f32) | flag (int)
  u16*   hws  = (u16*)d_ws;
  float* sq   = (float*)((char*)d_ws + (size_t)N_NODES * O_DIM * 2);
  float* sk   = sq + N_NODES;
  int*   flag = (int*)(sk + N_NODES);

  k_detect <<<1, 256, 0, stream>>>((const u32*)tm, flag);
  const int nrb = (N_NODES + BM - 1) / BM;   // 782
  k_gemm1  <<<nrb, 512, 0, stream>>>(x, fc1w, fc1b, xencw, xencb, hws);
  k_rowhead<<<(N_NODES + RH_ROWS - 1) / RH_ROWS, 256, 0, stream>>>(
      hws, y, tm, fc2w, fc2b, pw, flag, out + 2 * (size_t)E_NUM, sq, sk);
  k_edges  <<<E_NUM / 256, 256, 0, stream>>>(ei, ein, sq, sk, pb, out);
}

// Round 4
// 322.091 us; speedup vs baseline: 2.4271x; 2.4271x over previous
//
#include <hip/hip_runtime.h>
#include <stdint.h>

#define N_NODES 100000
#define F_DIM   500
#define C_DIM   40
#define H_DIM   256
#define HX_DIM  64
#define O_DIM   320   // H + HX
#define E_NUM   1600000

typedef unsigned short u16;
typedef unsigned int   u32;
typedef __attribute__((ext_vector_type(4))) u16    u16x4;
typedef __attribute__((ext_vector_type(8))) u16    u16x8;
typedef __attribute__((ext_vector_type(4))) float  f32x4;
typedef __attribute__((ext_vector_type(8))) short  bf16x8;  // MFMA A/B frag

__device__ __forceinline__ float bf2f(u16 v) {
  u32 u = ((u32)v) << 16;
  return __builtin_bit_cast(float, u);
}
__device__ __forceinline__ u16 f2bf(float f) {   // round-to-nearest-even
  u32 x = __builtin_bit_cast(u32, f);
  x += 0x7fffu + ((x >> 16) & 1u);
  return (u16)(x >> 16);
}

// ---------------- Kernel 0: train_mask encoding detector ----------------
// int32 0/1 mask: every u32 word is 0 or 1. byte-bool: words pack 4 bools ->
// P(word looks int-like) = 1/8; scanning 4096 words makes misdetection ~8^-4096.
__global__ __launch_bounds__(256) void k_detect(const u32* __restrict__ tm, int* __restrict__ flag)
{
  __shared__ int s;
  if (threadIdx.x == 0) s = 0;
  __syncthreads();
  int local = 0;
  #pragma unroll
  for (int j = 0; j < 16; ++j) {
    if (tm[j * 256 + threadIdx.x] > 1u) local = 1;
  }
  if (local) s = 1;             // benign race: all writers store 1
  __syncthreads();
  if (threadIdx.x == 0) *flag = s;
}

// ---------------- Kernel 1: [h|xe] = relu(x @ [fc1_w;xenc_w]^T + b) ----------------
#define BM  128
#define BN  320
#define LDX 40

__device__ __forceinline__ void stage_load(
    int tid, int kc, long rowbase,
    const float* __restrict__ x, const float* __restrict__ fc1w, const float* __restrict__ xencw,
    f32x4 st[7])
{
  #pragma unroll
  for (int j = 0; j < 7; ++j) {
    const int g  = tid + 512 * j;            // 3584 groups: 1024 A + 2560 B
    const int k0 = kc * 32 + (g & 7) * 4;
    const bool kval = (k0 + 4 <= F_DIM);     // F%4==0: float4 fully valid or fully OOB
    f32x4 v = (f32x4){0.f, 0.f, 0.f, 0.f};
    if (g < 1024) {
      const long rr = rowbase + (g >> 3);
      if (kval && rr < N_NODES) v = *(const f32x4*)(x + rr * F_DIM + k0);
    } else {
      const int o = (g - 1024) >> 3;
      if (kval) {
        const float* p = (o < H_DIM) ? (fc1w + (long)o * F_DIM + k0)
                                     : (xencw + (long)(o - H_DIM) * F_DIM + k0);
        v = *(const f32x4*)p;
      }
    }
    st[j] = v;
  }
}

__device__ __forceinline__ void stage_store(int tid, u16* __restrict__ sA, u16* __restrict__ sB,
                                            const f32x4 st[7])
{
  #pragma unroll
  for (int j = 0; j < 7; ++j) {
    const int g = tid + 512 * j;
    u16x4 b;
    #pragma unroll
    for (int i = 0; i < 4; ++i) b[i] = f2bf(st[j][i]);
    u16* dst;
    if (g < 1024) dst = sA + (g >> 3) * LDX + (g & 7) * 4;
    else          dst = sB + ((g - 1024) >> 3) * LDX + (g & 7) * 4;
    *(u16x4*)dst = b;
  }
}

__global__ __launch_bounds__(512) void k_gemm1(
    const float* __restrict__ x, const float* __restrict__ fc1w, const float* __restrict__ fc1b,
    const float* __restrict__ xencw, const float* __restrict__ xencb, u16* __restrict__ hout)
{
  __shared__ u16 sA[2][BM * LDX];
  __shared__ u16 sB[2][BN * LDX];
  const int tid  = threadIdx.x;
  const int lane = tid & 63;
  const int wid  = tid >> 6;
  const int wr = wid >> 2, wc = wid & 3;
  const long rowbase = (long)blockIdx.x * BM;

  f32x4 acc[4][5];
  #pragma unroll
  for (int m = 0; m < 4; ++m)
    #pragma unroll
    for (int n = 0; n < 5; ++n)
      acc[m][n] = (f32x4){0.f, 0.f, 0.f, 0.f};

  f32x4 st[7];
  stage_load(tid, 0, rowbase, x, fc1w, xencw, st);
  stage_store(tid, &sA[0][0], &sB[0][0], st);
  __syncthreads();

  for (int kc = 0; kc < 16; ++kc) {
    const int cur = kc & 1;
    if (kc < 15) stage_load(tid, kc + 1, rowbase, x, fc1w, xencw, st);

    bf16x8 a[4], b[5];
    const u16* pa = &sA[cur][(wr * 64 + (lane & 15)) * LDX + (lane >> 4) * 8];
    #pragma unroll
    for (int m = 0; m < 4; ++m) a[m] = *(const bf16x8*)(pa + m * 16 * LDX);
    const u16* pb = &sB[cur][(wc * 80 + (lane & 15)) * LDX + (lane >> 4) * 8];
    #pragma unroll
    for (int n = 0; n < 5; ++n) b[n] = *(const bf16x8*)(pb + n * 16 * LDX);

    #pragma unroll
    for (int m = 0; m < 4; ++m)
      #pragma unroll
      for (int n = 0; n < 5; ++n)
        acc[m][n] = __builtin_amdgcn_mfma_f32_16x16x32_bf16(a[m], b[n], acc[m][n], 0, 0, 0);

    if (kc < 15) stage_store(tid, &sA[cur ^ 1][0], &sB[cur ^ 1][0], st);
    __syncthreads();
  }

  // epilogue: bias + relu + bf16 store. C/D: col=lane&15, row=(lane>>4)*4+reg.
  #pragma unroll
  for (int n = 0; n < 5; ++n) {
    const int col = wc * 80 + n * 16 + (lane & 15);
    const float bias = (col < H_DIM) ? fc1b[col] : xencb[col - H_DIM];
    #pragma unroll
    for (int m = 0; m < 4; ++m) {
      const long row0 = rowbase + wr * 64 + m * 16 + ((lane >> 4) << 2);
      #pragma unroll
      for (int rg = 0; rg < 4; ++rg) {
        const long rr = row0 + rg;
        if (rr < N_NODES) {
          const float v = fmaxf(acc[m][n][rg] + bias, 0.f);
          hout[rr * O_DIM + col] = f2bf(v);
        }
      }
    }
  }
}

// ---------------- Kernel 2: MFMA row head ----------------
// Per block (128 thr, 2 waves): 32 rows. A = hws rows (32x320 bf16 in LDS),
// B' = 48x320 bf16 in LDS: rows 0-39 [fc2w | 0], row 40 [0 | w_xq],
// row 41 [0 | w_xk], rows 42-47 zero. One MFMA pass (10 K-steps, 3 N-frags)
// -> logits cols 0-39 plus xe-dot-w_xq/w_xk at cols 40/41. Softmax + s_q/s_k
// on the C/D layout (row r in 16 lanes of group r>>2 at reg r&3) via 16-lane
// shfl_xor reductions. Stride 328 u16 -> rows offset 4 banks, period 8 ->
// 2-way aliasing only (free per m136).
#define RH_BM 32
#define RH_LD 328

__global__ __launch_bounds__(128) void k_rowhead(
    const u16* __restrict__ hws, const int* __restrict__ y, const void* __restrict__ tmask,
    const float* __restrict__ fc2w, const float* __restrict__ fc2b, const float* __restrict__ pw,
    const int* __restrict__ mask_flag,
    float* __restrict__ out_lp, float* __restrict__ sq_out, float* __restrict__ sk_out)
{
  __shared__ u16 sA[RH_BM * RH_LD];   // 20992 B
  __shared__ u16 sB[48 * RH_LD];      // 31488 B  (52480 total)
  const int tid = threadIdx.x;
  const int lane = tid & 63, wid = tid >> 6;
  const int l15 = lane & 15, lgrp = lane >> 4;
  const long rowbase = (long)blockIdx.x * RH_BM;   // 3125*32 == 100000 exactly

  // ---- stage A: 32 rows x 40 groups, coalesced u16x8 ----
  #pragma unroll
  for (int it = 0; it < 10; ++it) {
    const int g = it * 128 + tid;
    const int r = g / 40, c = g - r * 40;
    *(u16x8*)&sA[r * RH_LD + c * 8] =
        *(const u16x8*)(hws + (rowbase + r) * O_DIM + c * 8);
  }
  // ---- stage B': 48 rows x 40 groups ----
  #pragma unroll
  for (int it = 0; it < 15; ++it) {
    const int g = it * 128 + tid;
    const int r = g / 40, c = g - r * 40;
    const int k0 = c * 8;
    u16x8 v = {0, 0, 0, 0, 0, 0, 0, 0};
    const float* src = nullptr;
    if (r < C_DIM) { if (k0 < H_DIM) src = fc2w + r * H_DIM + k0; }
    else if (r == C_DIM)     { if (k0 >= H_DIM) src = pw + (k0 - H_DIM); }           // w_xq
    else if (r == C_DIM + 1) { if (k0 >= H_DIM) src = pw + HX_DIM + (k0 - H_DIM); }  // w_xk
    if (src) {
      const f32x4 v0 = *(const f32x4*)src;
      const f32x4 v1 = *(const f32x4*)(src + 4);
      #pragma unroll
      for (int i = 0; i < 4; ++i) { v[i] = f2bf(v0[i]); v[4 + i] = f2bf(v1[i]); }
    }
    *(u16x8*)&sB[r * RH_LD + c * 8] = v;
  }
  __syncthreads();

  // ---- MFMA: wave wid handles rows wid*16..+16; 3 N-frags x 10 K-steps ----
  f32x4 acc[3];
  #pragma unroll
  for (int n = 0; n < 3; ++n) acc[n] = (f32x4){0.f, 0.f, 0.f, 0.f};
  const u16* pa = &sA[(wid * 16 + l15) * RH_LD + lgrp * 8];
  const u16* pb = &sB[l15 * RH_LD + lgrp * 8];
  #pragma unroll
  for (int kc = 0; kc < 10; ++kc) {
    const bf16x8 a = *(const bf16x8*)(pa + kc * 32);
    #pragma unroll
    for (int n = 0; n < 3; ++n) {
      const bf16x8 b = *(const bf16x8*)(pb + n * 16 * RH_LD + kc * 32);
      acc[n] = __builtin_amdgcn_mfma_f32_16x16x32_bf16(a, b, acc[n], 0, 0, 0);
    }
  }

  // ---- per-lane constants ----
  const int c0 = l15, c1 = 16 + l15, c2 = 32 + l15;   // c2 a logit only if l15<8
  const bool v2 = (l15 < 8);
  const float b0 = fc2b[c0], b1 = fc2b[c1], b2 = v2 ? fc2b[c2] : 0.f;
  const float wq0 = pw[2 * HX_DIM + c0], wq1 = pw[2 * HX_DIM + c1],
              wq2 = v2 ? pw[2 * HX_DIM + c2] : 0.f;
  const float wk0 = pw[2 * HX_DIM + C_DIM + c0], wk1 = pw[2 * HX_DIM + C_DIM + c1],
              wk2 = v2 ? pw[2 * HX_DIM + C_DIM + c2] : 0.f;
  const bool byte_mask = (*mask_flag != 0);

  // ---- softmax + s_q/s_k per output row (4 rows per 16-lane group) ----
  #pragma unroll
  for (int rg = 0; rg < 4; ++rg) {
    const long row = rowbase + wid * 16 + lgrp * 4 + rg;
    const float lg0 = acc[0][rg] + b0;
    const float lg1 = acc[1][rg] + b1;
    const float lg2 = acc[2][rg] + b2;
    const float sxq = __shfl(acc[2][rg], (lane & 48) | 8, 64);   // col 40: xe.w_xq
    const float sxk = __shfl(acc[2][rg], (lane & 48) | 9, 64);   // col 41: xe.w_xk

    float m = fmaxf(lg0, lg1);
    if (v2) m = fmaxf(m, lg2);
    #pragma unroll
    for (int off = 1; off < 16; off <<= 1) m = fmaxf(m, __shfl_xor(m, off, 64));
    const float e0 = __expf(lg0 - m), e1 = __expf(lg1 - m),
                e2 = v2 ? __expf(lg2 - m) : 0.f;
    float s = e0 + e1 + e2;
    #pragma unroll
    for (int off = 1; off < 16; off <<= 1) s += __shfl_xor(s, off, 64);
    const float lse = m + __logf(s);
    const float inv = 1.f / s;

    const int yv = y[row];
    const bool tm = byte_mask ? (((const unsigned char*)tmask)[row] != 0)
                              : (((const int*)tmask)[row] != 0);
    const float p0 = tm ? (c0 == yv ? 1.f : 0.f) : e0 * inv;
    const float p1 = tm ? (c1 == yv ? 1.f : 0.f) : e1 * inv;
    const float p2 = tm ? (c2 == yv ? 1.f : 0.f) : e2 * inv;   // c2>=40 never == yv
    float sq = p0 * wq0 + p1 * wq1 + p2 * wq2;
    float sk = p0 * wk0 + p1 * wk1 + p2 * wk2;
    #pragma unroll
    for (int off = 1; off < 16; off <<= 1) {
      sq += __shfl_xor(sq, off, 64);
      sk += __shfl_xor(sk, off, 64);
    }

    float* lp = out_lp + row * C_DIM;
    lp[c0] = lg0 - lse;
    lp[c1] = lg1 - lse;
    if (v2) lp[c2] = lg2 - lse;
    if (l15 == 0) { sq_out[row] = sq + sxq; sk_out[row] = sk + sxk; }
  }
}

// ---------------- Kernel 3: edge scores ----------------
__global__ __launch_bounds__(256) void k_edges(
    const int* __restrict__ ei, const int* __restrict__ ein,
    const float* __restrict__ sq, const float* __restrict__ sk,
    const float* __restrict__ pb, float* __restrict__ out)
{
  const int e = blockIdx.x * 256 + threadIdx.x;
  if (e >= E_NUM) return;
  const float b = pb[0];
  const int a0 = ei[e],  a1 = ei[E_NUM + e];
  out[e] = sq[a0] + sk[a1] + b;
  const int c0 = ein[e], c1 = ein[E_NUM + e];
  out[E_NUM + e] = sq[c0] + sk[c1] + b;
}

extern "C" void kernel_launch(void* const* d_in, const int* in_sizes, int n_in,
                              void* d_out, int out_size, void* d_ws, size_t ws_size,
                              hipStream_t stream)
{
  const float* x     = (const float*)d_in[0];
  const int*   y     = (const int*)d_in[1];
  const void*  tm    = d_in[2];
  const int*   ei    = (const int*)d_in[3];
  const int*   ein   = (const int*)d_in[4];
  const float* fc1w  = (const float*)d_in[5];
  const float* fc1b  = (const float*)d_in[6];
  const float* fc2w  = (const float*)d_in[7];
  const float* fc2b  = (const float*)d_in[8];
  const float* xencw = (const float*)d_in[9];
  const float* xencb = (const float*)d_in[10];
  const float* pw    = (const float*)d_in[11];
  const float* pb    = (const float*)d_in[12];
  float* out = (float*)d_out;

  // workspace: h|xe (N x 320 bf16, 64 MB) | s_q (N f32) | s_k (N f32) | flag (int)
  u16*   hws  = (u16*)d_ws;
  float* sq   = (float*)((char*)d_ws + (size_t)N_NODES * O_DIM * 2);
  float* sk   = sq + N_NODES;
  int*   flag = (int*)(sk + N_NODES);

  k_detect <<<1, 256, 0, stream>>>((const u32*)tm, flag);
  const int nrb = (N_NODES + BM - 1) / BM;   // 782
  k_gemm1  <<<nrb, 512, 0, stream>>>(x, fc1w, fc1b, xencw, xencb, hws);
  k_rowhead<<<N_NODES / RH_BM, 128, 0, stream>>>(
      hws, y, tm, fc2w, fc2b, pw, flag, out + 2 * (size_t)E_NUM, sq, sk);
  k_edges  <<<E_NUM / 256, 256, 0, stream>>>(ei, ein, sq, sk, pb, out);
}

// Round 5
// 207.369 us; speedup vs baseline: 3.7698x; 1.5532x over previous
//
#include <hip/hip_runtime.h>
#include <stdint.h>

#define N_NODES 100000
#define F_DIM   500
#define C_DIM   40
#define H_DIM   256
#define HX_DIM  64
#define O_DIM   320   // H + HX
#define E_NUM   1600000

typedef unsigned short u16;
typedef unsigned int   u32;
typedef __attribute__((ext_vector_type(4))) u16    u16x4;
typedef __attribute__((ext_vector_type(8))) u16    u16x8;
typedef __attribute__((ext_vector_type(4))) float  f32x4;
typedef __attribute__((ext_vector_type(8))) short  bf16x8;  // MFMA A/B frag

__device__ __forceinline__ float bf2f(u16 v) {
  u32 u = ((u32)v) << 16;
  return __builtin_bit_cast(float, u);
}
__device__ __forceinline__ u16 f2bf(float f) {   // round-to-nearest-even
  u32 x = __builtin_bit_cast(u32, f);
  x += 0x7fffu + ((x >> 16) & 1u);
  return (u16)(x >> 16);
}

// ---------------- Kernel 0: train_mask encoding detector ----------------
__global__ __launch_bounds__(256) void k_detect(const u32* __restrict__ tm, int* __restrict__ flag)
{
  __shared__ int s;
  if (threadIdx.x == 0) s = 0;
  __syncthreads();
  int local = 0;
  #pragma unroll
  for (int j = 0; j < 16; ++j) {
    if (tm[j * 256 + threadIdx.x] > 1u) local = 1;
  }
  if (local) s = 1;
  __syncthreads();
  if (threadIdx.x == 0) *flag = s;
}

// ---------------- Kernel 0b: pre-convert W=[fc1_w;xenc_w] to bf16, K-chunked ----------------
// Layout: chunk c (K 32-slice), row r (0..319), logical slot s (8 bf16):
//   wws[c*10240 + r*32 + s*8 + j] = bf16(W[r][c*32 + s*8 + j]), zero-padded past K=500.
// GEMM B-staging then reads 20 KB CONTIGUOUS per K-step.
__global__ __launch_bounds__(256) void k_cvtw(
    const float* __restrict__ fc1w, const float* __restrict__ xencw, u16* __restrict__ wws)
{
  const int g = blockIdx.x * 256 + threadIdx.x;   // 20480 groups
  const int c = g / 1280;
  const int rem = g - c * 1280;
  const int r = rem >> 2;
  const int k0 = c * 32 + (rem & 3) * 8;
  const float* src = (r < H_DIM) ? (fc1w + (long)r * F_DIM)
                                 : (xencw + (long)(r - H_DIM) * F_DIM);
  f32x4 v0 = {0.f, 0.f, 0.f, 0.f}, v1 = v0;
  if (k0 + 4 <= F_DIM) v0 = *(const f32x4*)(src + k0);
  if (k0 + 8 <= F_DIM) v1 = *(const f32x4*)(src + k0 + 4);
  u16x8 o;
  #pragma unroll
  for (int i = 0; i < 4; ++i) { o[i] = f2bf(v0[i]); o[4 + i] = f2bf(v1[i]); }
  *(u16x8*)(wws + (size_t)g * 8) = o;
}

// ---------------- Kernel 1: [h|xe] = relu(x @ W^T + b) ----------------
// BM=64 x BN=320, BK=32, 256 thr (4 waves = 4 N-strips of 80). LDS 48 KB -> 3 blocks/CU.
// XOR slot swizzle: phys_slot = logical_slot ^ ((row>>1)&3) -> exactly 2 lanes/bank on
// both ds_write_b128 and frag ds_read_b128 (free per m136). Write & read swizzle live
// in this kernel only (both-sides rule).
#define G_BM 64
#define G_BK 32
#define BN   320

__global__ __launch_bounds__(256, 3) void k_gemm1(
    const float* __restrict__ x, const u16* __restrict__ wws,
    const float* __restrict__ fc1b, const float* __restrict__ xencb,
    u16* __restrict__ hout)
{
  __shared__ u16 sA[2][G_BM * G_BK];   // 2 * 4 KB
  __shared__ u16 sB[2][BN * G_BK];     // 2 * 20 KB
  const int tid  = threadIdx.x;
  const int lane = tid & 63;
  const int wc   = tid >> 6;                 // N-strip
  const int l15 = lane & 15, lgrp = lane >> 4;
  const long rowbase = (long)blockIdx.x * G_BM;

  // staging geometry: thread t -> row ar=t>>2, logical slot as=t&3
  const int ar  = tid >> 2;
  const int as  = tid & 3;
  const int aps = as ^ ((ar >> 1) & 3);      // physical slot (write-side swizzle)
  const long arow = rowbase + ar;
  const bool arv = (arow < N_NODES);
  const float* xrow = x + arow * F_DIM;

  const int rslot = (lgrp ^ ((l15 >> 1) & 3)) * 8;   // read-side swizzle (lane-const)

  f32x4 acc[4][5];
  #pragma unroll
  for (int m = 0; m < 4; ++m)
    #pragma unroll
    for (int n = 0; n < 5; ++n)
      acc[m][n] = (f32x4){0.f, 0.f, 0.f, 0.f};

  f32x4 a0, a1;
  u16x8 breg[5];

#define LOAD_AB(kc)                                                          \
  {                                                                          \
    const int k0 = (kc) * G_BK + as * 8;                                     \
    a0 = (f32x4){0.f, 0.f, 0.f, 0.f}; a1 = a0;                               \
    if (arv && k0 + 4 <= F_DIM) a0 = *(const f32x4*)(xrow + k0);             \
    if (arv && k0 + 8 <= F_DIM) a1 = *(const f32x4*)(xrow + k0 + 4);         \
    const u16* bp = wws + (size_t)(kc) * (BN * G_BK) + tid * 8;              \
    _Pragma("unroll")                                                        \
    for (int j = 0; j < 5; ++j) breg[j] = *(const u16x8*)(bp + j * 2048);    \
  }

#define STORE_AB(buf)                                                        \
  {                                                                          \
    u16x8 av;                                                                \
    _Pragma("unroll")                                                        \
    for (int i = 0; i < 4; ++i) { av[i] = f2bf(a0[i]); av[4 + i] = f2bf(a1[i]); } \
    *(u16x8*)&sA[buf][ar * G_BK + aps * 8] = av;                             \
    _Pragma("unroll")                                                        \
    for (int j = 0; j < 5; ++j)                                              \
      *(u16x8*)&sB[buf][(ar + j * 64) * G_BK + aps * 8] = breg[j];           \
  }

  LOAD_AB(0);
  STORE_AB(0);
  __syncthreads();

  for (int kc = 0; kc < 16; ++kc) {
    const int cur = kc & 1;
    if (kc < 15) LOAD_AB(kc + 1);          // issue early: overlaps the MFMA below

    bf16x8 bfr[5];
    #pragma unroll
    for (int n = 0; n < 5; ++n)
      bfr[n] = *(const bf16x8*)&sB[cur][(wc * 80 + n * 16 + l15) * G_BK + rslot];
    #pragma unroll
    for (int m = 0; m < 4; ++m) {
      const bf16x8 afr = *(const bf16x8*)&sA[cur][(m * 16 + l15) * G_BK + rslot];
      #pragma unroll
      for (int n = 0; n < 5; ++n)
        acc[m][n] = __builtin_amdgcn_mfma_f32_16x16x32_bf16(afr, bfr[n], acc[m][n], 0, 0, 0);
    }

    if (kc < 15) STORE_AB(cur ^ 1);        // compiler waits vmcnt on a0/a1/breg here
    __syncthreads();
  }

  // epilogue: bias + relu + bf16 store. C/D: col=lane&15, row=(lane>>4)*4+reg.
  #pragma unroll
  for (int n = 0; n < 5; ++n) {
    const int col = wc * 80 + n * 16 + l15;
    const float bias = (col < H_DIM) ? fc1b[col] : xencb[col - H_DIM];
    #pragma unroll
    for (int m = 0; m < 4; ++m) {
      const long row0 = rowbase + m * 16 + lgrp * 4;
      #pragma unroll
      for (int rg = 0; rg < 4; ++rg) {
        const long rr = row0 + rg;
        if (rr < N_NODES) {
          const float v = fmaxf(acc[m][n][rg] + bias, 0.f);
          hout[rr * O_DIM + col] = f2bf(v);
        }
      }
    }
  }
#undef LOAD_AB
#undef STORE_AB
}

// ---------------- Kernel 2: MFMA row head (validated round 4) ----------------
#define RH_BM 32
#define RH_LD 328

__global__ __launch_bounds__(128) void k_rowhead(
    const u16* __restrict__ hws, const int* __restrict__ y, const void* __restrict__ tmask,
    const float* __restrict__ fc2w, const float* __restrict__ fc2b, const float* __restrict__ pw,
    const int* __restrict__ mask_flag,
    float* __restrict__ out_lp, float* __restrict__ sq_out, float* __restrict__ sk_out)
{
  __shared__ u16 sA[RH_BM * RH_LD];
  __shared__ u16 sB[48 * RH_LD];
  const int tid = threadIdx.x;
  const int lane = tid & 63, wid = tid >> 6;
  const int l15 = lane & 15, lgrp = lane >> 4;
  const long rowbase = (long)blockIdx.x * RH_BM;

  #pragma unroll
  for (int it = 0; it < 10; ++it) {
    const int g = it * 128 + tid;
    const int r = g / 40, c = g - r * 40;
    *(u16x8*)&sA[r * RH_LD + c * 8] =
        *(const u16x8*)(hws + (rowbase + r) * O_DIM + c * 8);
  }
  #pragma unroll
  for (int it = 0; it < 15; ++it) {
    const int g = it * 128 + tid;
    const int r = g / 40, c = g - r * 40;
    const int k0 = c * 8;
    u16x8 v = {0, 0, 0, 0, 0, 0, 0, 0};
    const float* src = nullptr;
    if (r < C_DIM) { if (k0 < H_DIM) src = fc2w + r * H_DIM + k0; }
    else if (r == C_DIM)     { if (k0 >= H_DIM) src = pw + (k0 - H_DIM); }
    else if (r == C_DIM + 1) { if (k0 >= H_DIM) src = pw + HX_DIM + (k0 - H_DIM); }
    if (src) {
      const f32x4 v0 = *(const f32x4*)src;
      const f32x4 v1 = *(const f32x4*)(src + 4);
      #pragma unroll
      for (int i = 0; i < 4; ++i) { v[i] = f2bf(v0[i]); v[4 + i] = f2bf(v1[i]); }
    }
    *(u16x8*)&sB[r * RH_LD + c * 8] = v;
  }
  __syncthreads();

  f32x4 acc[3];
  #pragma unroll
  for (int n = 0; n < 3; ++n) acc[n] = (f32x4){0.f, 0.f, 0.f, 0.f};
  const u16* pa = &sA[(wid * 16 + l15) * RH_LD + lgrp * 8];
  const u16* pb = &sB[l15 * RH_LD + lgrp * 8];
  #pragma unroll
  for (int kc = 0; kc < 10; ++kc) {
    const bf16x8 a = *(const bf16x8*)(pa + kc * 32);
    #pragma unroll
    for (int n = 0; n < 3; ++n) {
      const bf16x8 b = *(const bf16x8*)(pb + n * 16 * RH_LD + kc * 32);
      acc[n] = __builtin_amdgcn_mfma_f32_16x16x32_bf16(a, b, acc[n], 0, 0, 0);
    }
  }

  const int c0 = l15, c1 = 16 + l15, c2 = 32 + l15;
  const bool v2 = (l15 < 8);
  const float b0 = fc2b[c0], b1 = fc2b[c1], b2 = v2 ? fc2b[c2] : 0.f;
  const float wq0 = pw[2 * HX_DIM + c0], wq1 = pw[2 * HX_DIM + c1],
              wq2 = v2 ? pw[2 * HX_DIM + c2] : 0.f;
  const float wk0 = pw[2 * HX_DIM + C_DIM + c0], wk1 = pw[2 * HX_DIM + C_DIM + c1],
              wk2 = v2 ? pw[2 * HX_DIM + C_DIM + c2] : 0.f;
  const bool byte_mask = (*mask_flag != 0);

  #pragma unroll
  for (int rg = 0; rg < 4; ++rg) {
    const long row = rowbase + wid * 16 + lgrp * 4 + rg;
    const float lg0 = acc[0][rg] + b0;
    const float lg1 = acc[1][rg] + b1;
    const float lg2 = acc[2][rg] + b2;
    const float sxq = __shfl(acc[2][rg], (lane & 48) | 8, 64);
    const float sxk = __shfl(acc[2][rg], (lane & 48) | 9, 64);

    float m = fmaxf(lg0, lg1);
    if (v2) m = fmaxf(m, lg2);
    #pragma unroll
    for (int off = 1; off < 16; off <<= 1) m = fmaxf(m, __shfl_xor(m, off, 64));
    const float e0 = __expf(lg0 - m), e1 = __expf(lg1 - m),
                e2 = v2 ? __expf(lg2 - m) : 0.f;
    float s = e0 + e1 + e2;
    #pragma unroll
    for (int off = 1; off < 16; off <<= 1) s += __shfl_xor(s, off, 64);
    const float lse = m + __logf(s);
    const float inv = 1.f / s;

    const int yv = y[row];
    const bool tm = byte_mask ? (((const unsigned char*)tmask)[row] != 0)
                              : (((const int*)tmask)[row] != 0);
    const float p0 = tm ? (c0 == yv ? 1.f : 0.f) : e0 * inv;
    const float p1 = tm ? (c1 == yv ? 1.f : 0.f) : e1 * inv;
    const float p2 = tm ? (c2 == yv ? 1.f : 0.f) : e2 * inv;
    float sq = p0 * wq0 + p1 * wq1 + p2 * wq2;
    float sk = p0 * wk0 + p1 * wk1 + p2 * wk2;
    #pragma unroll
    for (int off = 1; off < 16; off <<= 1) {
      sq += __shfl_xor(sq, off, 64);
      sk += __shfl_xor(sk, off, 64);
    }

    float* lp = out_lp + row * C_DIM;
    lp[c0] = lg0 - lse;
    lp[c1] = lg1 - lse;
    if (v2) lp[c2] = lg2 - lse;
    if (l15 == 0) { sq_out[row] = sq + sxq; sk_out[row] = sk + sxk; }
  }
}

// ---------------- Kernel 3: edge scores ----------------
__global__ __launch_bounds__(256) void k_edges(
    const int* __restrict__ ei, const int* __restrict__ ein,
    const float* __restrict__ sq, const float* __restrict__ sk,
    const float* __restrict__ pb, float* __restrict__ out)
{
  const int e = blockIdx.x * 256 + threadIdx.x;
  if (e >= E_NUM) return;
  const float b = pb[0];
  const int a0 = ei[e],  a1 = ei[E_NUM + e];
  out[e] = sq[a0] + sk[a1] + b;
  const int c0 = ein[e], c1 = ein[E_NUM + e];
  out[E_NUM + e] = sq[c0] + sk[c1] + b;
}

extern "C" void kernel_launch(void* const* d_in, const int* in_sizes, int n_in,
                              void* d_out, int out_size, void* d_ws, size_t ws_size,
                              hipStream_t stream)
{
  const float* x     = (const float*)d_in[0];
  const int*   y     = (const int*)d_in[1];
  const void*  tm    = d_in[2];
  const int*   ei    = (const int*)d_in[3];
  const int*   ein   = (const int*)d_in[4];
  const float* fc1w  = (const float*)d_in[5];
  const float* fc1b  = (const float*)d_in[6];
  const float* fc2w  = (const float*)d_in[7];
  const float* fc2b  = (const float*)d_in[8];
  const float* xencw = (const float*)d_in[9];
  const float* xencb = (const float*)d_in[10];
  const float* pw    = (const float*)d_in[11];
  const float* pb    = (const float*)d_in[12];
  float* out = (float*)d_out;

  // ws: hws (N*320 bf16 = 64 MB) | s_q (N f32) | s_k (N f32) | flag | wws (320 KB)
  u16*   hws  = (u16*)d_ws;
  float* sq   = (float*)((char*)d_ws + (size_t)N_NODES * O_DIM * 2);
  float* sk   = sq + N_NODES;
  int*   flag = (int*)(sk + N_NODES);
  u16*   wws  = (u16*)((char*)d_ws + 64800064);   // 64-byte aligned

  k_detect<<<1, 256, 0, stream>>>((const u32*)tm, flag);
  k_cvtw  <<<80, 256, 0, stream>>>(fc1w, xencw, wws);
  const int nrb = (N_NODES + G_BM - 1) / G_BM;    // 1563
  k_gemm1 <<<nrb, 256, 0, stream>>>(x, wws, fc1b, xencb, hws);
  k_rowhead<<<N_NODES / RH_BM, 128, 0, stream>>>(
      hws, y, tm, fc2w, fc2b, pw, flag, out + 2 * (size_t)E_NUM, sq, sk);
  k_edges <<<E_NUM / 256, 256, 0, stream>>>(ei, ein, sq, sk, pb, out);
}

// Round 6
// 180.766 us; speedup vs baseline: 4.3246x; 1.1472x over previous
//
#include <hip/hip_runtime.h>
#include <stdint.h>

#define N_NODES 100000
#define F_DIM   500
#define C_DIM   40
#define H_DIM   256
#define HX_DIM  64
#define O_DIM   320   // H + HX
#define E_NUM   1600000

typedef unsigned short u16;
typedef unsigned int   u32;
typedef __attribute__((ext_vector_type(4))) u16    u16x4;
typedef __attribute__((ext_vector_type(8))) u16    u16x8;
typedef __attribute__((ext_vector_type(4))) float  f32x4;
typedef __attribute__((ext_vector_type(8))) short  bf16x8;  // MFMA A/B frag

__device__ __forceinline__ float bf2f(u16 v) {
  u32 u = ((u32)v) << 16;
  return __builtin_bit_cast(float, u);
}
__device__ __forceinline__ u16 f2bf(float f) {   // round-to-nearest-even
  u32 x = __builtin_bit_cast(u32, f);
  x += 0x7fffu + ((x >> 16) & 1u);
  return (u16)(x >> 16);
}

// ---------------- Kernel 0: train_mask encoding detector ----------------
__global__ __launch_bounds__(256) void k_detect(const u32* __restrict__ tm, int* __restrict__ flag)
{
  __shared__ int s;
  if (threadIdx.x == 0) s = 0;
  __syncthreads();
  int local = 0;
  #pragma unroll
  for (int j = 0; j < 16; ++j) {
    if (tm[j * 256 + threadIdx.x] > 1u) local = 1;
  }
  if (local) s = 1;
  __syncthreads();
  if (threadIdx.x == 0) *flag = s;
}

// ---------------- Kernel 0b: pre-convert W=[fc1_w;xenc_w] to bf16, K-chunked ----------------
// wws[c*10240 + r*32 + s*8 + j] = bf16(W[r][c*32+s*8+j]), zero-padded past K=500.
__global__ __launch_bounds__(256) void k_cvtw(
    const float* __restrict__ fc1w, const float* __restrict__ xencw, u16* __restrict__ wws)
{
  const int g = blockIdx.x * 256 + threadIdx.x;   // 20480 groups
  const int c = g / 1280;
  const int rem = g - c * 1280;
  const int r = rem >> 2;
  const int k0 = c * 32 + (rem & 3) * 8;
  const float* src = (r < H_DIM) ? (fc1w + (long)r * F_DIM)
                                 : (xencw + (long)(r - H_DIM) * F_DIM);
  f32x4 v0 = {0.f, 0.f, 0.f, 0.f}, v1 = v0;
  if (k0 + 4 <= F_DIM) v0 = *(const f32x4*)(src + k0);
  if (k0 + 8 <= F_DIM) v1 = *(const f32x4*)(src + k0 + 4);
  u16x8 o;
  #pragma unroll
  for (int i = 0; i < 4; ++i) { o[i] = f2bf(v0[i]); o[4 + i] = f2bf(v1[i]); }
  *(u16x8*)(wws + (size_t)g * 8) = o;
}

// ---------------- Kernel 1: [h|xe] = relu(x @ W^T + b) ----------------
// BM=64 x BN=320, BK=32, 256 thr (4 waves = 4 N-strips of 80).
// v3: whole x-tile preloaded to regs in prologue (areg[16], 64 VGPR) -> the K-loop
// has NO global x dependency; B (wws, L2-resident) prefetched 1 step ahead.
// LDS-staged epilogue for coalesced 16B writes (fixes 137 MB -> 64 MB write ampl).
#define G_BM 64
#define G_BK 32
#define BN   320
#define EP_LD 328   // epilogue LDS row stride (u16): 2-way max bank aliasing

__global__ __launch_bounds__(256, 2) void k_gemm1(
    const float* __restrict__ x, const u16* __restrict__ wws,
    const float* __restrict__ fc1b, const float* __restrict__ xencb,
    u16* __restrict__ hout)
{
  __shared__ char smem[49152];
  u16* sA0 = (u16*)smem;                    // 2 x 4 KB
  u16* sA1 = (u16*)(smem + 4096);
  u16* sB0 = (u16*)(smem + 8192);           // 2 x 20 KB
  u16* sB1 = (u16*)(smem + 28672);
  u16* sOut = (u16*)smem;                   // epilogue reuse: 64*328*2 = 41984 B

  const int tid  = threadIdx.x;
  const int lane = tid & 63;
  const int wc   = tid >> 6;                // N-strip
  const int l15 = lane & 15, lgrp = lane >> 4;
  const long rowbase = (long)blockIdx.x * G_BM;

  // staging geometry: thread t -> row ar=t>>2, logical slot as=t&3
  const int ar  = tid >> 2;
  const int as  = tid & 3;
  const int aps = as ^ ((ar >> 1) & 3);     // write-side slot swizzle
  const long arow = rowbase + ar;
  const bool arv = (arow < N_NODES);
  const float* xrow = x + arow * F_DIM;

  const int rslot = (lgrp ^ ((l15 >> 1) & 3)) * 8;   // read-side swizzle

  // ---- prologue: preload + pack the whole x-tile slice for this thread ----
  u16x8 areg[16];
  #pragma unroll
  for (int kc = 0; kc < 16; ++kc) {
    const int k0 = kc * G_BK + as * 8;
    f32x4 a0 = {0.f, 0.f, 0.f, 0.f}, a1 = a0;
    if (arv && k0 + 4 <= F_DIM) a0 = *(const f32x4*)(xrow + k0);
    if (arv && k0 + 8 <= F_DIM) a1 = *(const f32x4*)(xrow + k0 + 4);
    u16x8 av;
    #pragma unroll
    for (int i = 0; i < 4; ++i) { av[i] = f2bf(a0[i]); av[4 + i] = f2bf(a1[i]); }
    areg[kc] = av;
  }

  f32x4 acc[4][5];
  #pragma unroll
  for (int m = 0; m < 4; ++m)
    #pragma unroll
    for (int n = 0; n < 5; ++n)
      acc[m][n] = (f32x4){0.f, 0.f, 0.f, 0.f};

  u16x8 breg[5];
#define LOAD_B(kc)                                                           \
  {                                                                          \
    const u16* bp = wws + (size_t)(kc) * (BN * G_BK) + tid * 8;              \
    _Pragma("unroll")                                                        \
    for (int j = 0; j < 5; ++j) breg[j] = *(const u16x8*)(bp + j * 2048);    \
  }

  LOAD_B(0);
  *(u16x8*)(sA0 + ar * G_BK + aps * 8) = areg[0];
  #pragma unroll
  for (int j = 0; j < 5; ++j)
    *(u16x8*)(sB0 + (ar + j * 64) * G_BK + aps * 8) = breg[j];
  __syncthreads();

  #pragma unroll
  for (int kc = 0; kc < 16; ++kc) {
    const u16* sA = (kc & 1) ? sA1 : sA0;
    const u16* sB = (kc & 1) ? sB1 : sB0;
    u16* nA = (kc & 1) ? sA0 : sA1;
    u16* nB = (kc & 1) ? sB0 : sB1;

    if (kc < 15) LOAD_B(kc + 1);           // L2-resident; covered by MFMA below

    bf16x8 bfr[5];
    #pragma unroll
    for (int n = 0; n < 5; ++n)
      bfr[n] = *(const bf16x8*)(sB + (wc * 80 + n * 16 + l15) * G_BK + rslot);
    #pragma unroll
    for (int m = 0; m < 4; ++m) {
      const bf16x8 afr = *(const bf16x8*)(sA + (m * 16 + l15) * G_BK + rslot);
      #pragma unroll
      for (int n = 0; n < 5; ++n)
        acc[m][n] = __builtin_amdgcn_mfma_f32_16x16x32_bf16(afr, bfr[n], acc[m][n], 0, 0, 0);
    }

    if (kc < 15) {
      *(u16x8*)(nA + ar * G_BK + aps * 8) = areg[kc + 1];
      #pragma unroll
      for (int j = 0; j < 5; ++j)
        *(u16x8*)(nB + (ar + j * 64) * G_BK + aps * 8) = breg[j];
    }
    __syncthreads();
  }

  // ---- epilogue: bias+relu -> LDS (stride 328) -> coalesced 16B stores ----
  // C/D: col=lane&15, row=(lane>>4)*4+reg.
  #pragma unroll
  for (int n = 0; n < 5; ++n) {
    const int col = wc * 80 + n * 16 + l15;
    const float bias = (col < H_DIM) ? fc1b[col] : xencb[col - H_DIM];
    #pragma unroll
    for (int m = 0; m < 4; ++m) {
      const int r0 = m * 16 + lgrp * 4;
      #pragma unroll
      for (int rg = 0; rg < 4; ++rg)
        sOut[(r0 + rg) * EP_LD + col] = f2bf(fmaxf(acc[m][n][rg] + bias, 0.f));
    }
  }
  __syncthreads();
  #pragma unroll
  for (int it = 0; it < 10; ++it) {
    const int g = it * 256 + tid;          // 2560 groups: row r, 16B group c
    const int r = g / 40, c = g - r * 40;
    const long rr = rowbase + r;
    if (rr < N_NODES)
      *(u16x8*)(hout + rr * O_DIM + c * 8) = *(const u16x8*)&sOut[r * EP_LD + c * 8];
  }
#undef LOAD_B
}

// ---------------- Kernel 2: MFMA row head (validated round 4) ----------------
#define RH_BM 32
#define RH_LD 328

__global__ __launch_bounds__(128) void k_rowhead(
    const u16* __restrict__ hws, const int* __restrict__ y, const void* __restrict__ tmask,
    const float* __restrict__ fc2w, const float* __restrict__ fc2b, const float* __restrict__ pw,
    const int* __restrict__ mask_flag,
    float* __restrict__ out_lp, float* __restrict__ sq_out, float* __restrict__ sk_out)
{
  __shared__ u16 sA[RH_BM * RH_LD];
  __shared__ u16 sB[48 * RH_LD];
  const int tid = threadIdx.x;
  const int lane = tid & 63, wid = tid >> 6;
  const int l15 = lane & 15, lgrp = lane >> 4;
  const long rowbase = (long)blockIdx.x * RH_BM;

  #pragma unroll
  for (int it = 0; it < 10; ++it) {
    const int g = it * 128 + tid;
    const int r = g / 40, c = g - r * 40;
    *(u16x8*)&sA[r * RH_LD + c * 8] =
        *(const u16x8*)(hws + (rowbase + r) * O_DIM + c * 8);
  }
  #pragma unroll
  for (int it = 0; it < 15; ++it) {
    const int g = it * 128 + tid;
    const int r = g / 40, c = g - r * 40;
    const int k0 = c * 8;
    u16x8 v = {0, 0, 0, 0, 0, 0, 0, 0};
    const float* src = nullptr;
    if (r < C_DIM) { if (k0 < H_DIM) src = fc2w + r * H_DIM + k0; }
    else if (r == C_DIM)     { if (k0 >= H_DIM) src = pw + (k0 - H_DIM); }
    else if (r == C_DIM + 1) { if (k0 >= H_DIM) src = pw + HX_DIM + (k0 - H_DIM); }
    if (src) {
      const f32x4 v0 = *(const f32x4*)src;
      const f32x4 v1 = *(const f32x4*)(src + 4);
      #pragma unroll
      for (int i = 0; i < 4; ++i) { v[i] = f2bf(v0[i]); v[4 + i] = f2bf(v1[i]); }
    }
    *(u16x8*)&sB[r * RH_LD + c * 8] = v;
  }
  __syncthreads();

  f32x4 acc[3];
  #pragma unroll
  for (int n = 0; n < 3; ++n) acc[n] = (f32x4){0.f, 0.f, 0.f, 0.f};
  const u16* pa = &sA[(wid * 16 + l15) * RH_LD + lgrp * 8];
  const u16* pb = &sB[l15 * RH_LD + lgrp * 8];
  #pragma unroll
  for (int kc = 0; kc < 10; ++kc) {
    const bf16x8 a = *(const bf16x8*)(pa + kc * 32);
    #pragma unroll
    for (int n = 0; n < 3; ++n) {
      const bf16x8 b = *(const bf16x8*)(pb + n * 16 * RH_LD + kc * 32);
      acc[n] = __builtin_amdgcn_mfma_f32_16x16x32_bf16(a, b, acc[n], 0, 0, 0);
    }
  }

  const int c0 = l15, c1 = 16 + l15, c2 = 32 + l15;
  const bool v2 = (l15 < 8);
  const float b0 = fc2b[c0], b1 = fc2b[c1], b2 = v2 ? fc2b[c2] : 0.f;
  const float wq0 = pw[2 * HX_DIM + c0], wq1 = pw[2 * HX_DIM + c1],
              wq2 = v2 ? pw[2 * HX_DIM + c2] : 0.f;
  const float wk0 = pw[2 * HX_DIM + C_DIM + c0], wk1 = pw[2 * HX_DIM + C_DIM + c1],
              wk2 = v2 ? pw[2 * HX_DIM + C_DIM + c2] : 0.f;
  const bool byte_mask = (*mask_flag != 0);

  #pragma unroll
  for (int rg = 0; rg < 4; ++rg) {
    const long row = rowbase + wid * 16 + lgrp * 4 + rg;
    const float lg0 = acc[0][rg] + b0;
    const float lg1 = acc[1][rg] + b1;
    const float lg2 = acc[2][rg] + b2;
    const float sxq = __shfl(acc[2][rg], (lane & 48) | 8, 64);
    const float sxk = __shfl(acc[2][rg], (lane & 48) | 9, 64);

    float m = fmaxf(lg0, lg1);
    if (v2) m = fmaxf(m, lg2);
    #pragma unroll
    for (int off = 1; off < 16; off <<= 1) m = fmaxf(m, __shfl_xor(m, off, 64));
    const float e0 = __expf(lg0 - m), e1 = __expf(lg1 - m),
                e2 = v2 ? __expf(lg2 - m) : 0.f;
    float s = e0 + e1 + e2;
    #pragma unroll
    for (int off = 1; off < 16; off <<= 1) s += __shfl_xor(s, off, 64);
    const float lse = m + __logf(s);
    const float inv = 1.f / s;

    const int yv = y[row];
    const bool tm = byte_mask ? (((const unsigned char*)tmask)[row] != 0)
                              : (((const int*)tmask)[row] != 0);
    const float p0 = tm ? (c0 == yv ? 1.f : 0.f) : e0 * inv;
    const float p1 = tm ? (c1 == yv ? 1.f : 0.f) : e1 * inv;
    const float p2 = tm ? (c2 == yv ? 1.f : 0.f) : e2 * inv;
    float sq = p0 * wq0 + p1 * wq1 + p2 * wq2;
    float sk = p0 * wk0 + p1 * wk1 + p2 * wk2;
    #pragma unroll
    for (int off = 1; off < 16; off <<= 1) {
      sq += __shfl_xor(sq, off, 64);
      sk += __shfl_xor(sk, off, 64);
    }

    float* lp = out_lp + row * C_DIM;
    lp[c0] = lg0 - lse;
    lp[c1] = lg1 - lse;
    if (v2) lp[c2] = lg2 - lse;
    if (l15 == 0) { sq_out[row] = sq + sxq; sk_out[row] = sk + sxk; }
  }
}

// ---------------- Kernel 3: edge scores ----------------
__global__ __launch_bounds__(256) void k_edges(
    const int* __restrict__ ei, const int* __restrict__ ein,
    const float* __restrict__ sq, const float* __restrict__ sk,
    const float* __restrict__ pb, float* __restrict__ out)
{
  const int e = blockIdx.x * 256 + threadIdx.x;
  if (e >= E_NUM) return;
  const float b = pb[0];
  const int a0 = ei[e],  a1 = ei[E_NUM + e];
  out[e] = sq[a0] + sk[a1] + b;
  const int c0 = ein[e], c1 = ein[E_NUM + e];
  out[E_NUM + e] = sq[c0] + sk[c1] + b;
}

extern "C" void kernel_launch(void* const* d_in, const int* in_sizes, int n_in,
                              void* d_out, int out_size, void* d_ws, size_t ws_size,
                              hipStream_t stream)
{
  const float* x     = (const float*)d_in[0];
  const int*   y     = (const int*)d_in[1];
  const void*  tm    = d_in[2];
  const int*   ei    = (const int*)d_in[3];
  const int*   ein   = (const int*)d_in[4];
  const float* fc1w  = (const float*)d_in[5];
  const float* fc1b  = (const float*)d_in[6];
  const float* fc2w  = (const float*)d_in[7];
  const float* fc2b  = (const float*)d_in[8];
  const float* xencw = (const float*)d_in[9];
  const float* xencb = (const float*)d_in[10];
  const float* pw    = (const float*)d_in[11];
  const float* pb    = (const float*)d_in[12];
  float* out = (float*)d_out;

  // ws: hws (N*320 bf16 = 64 MB) | s_q | s_k | flag | wws (320 KB)
  u16*   hws  = (u16*)d_ws;
  float* sq   = (float*)((char*)d_ws + (size_t)N_NODES * O_DIM * 2);
  float* sk   = sq + N_NODES;
  int*   flag = (int*)(sk + N_NODES);
  u16*   wws  = (u16*)((char*)d_ws + 64800064);

  k_detect<<<1, 256, 0, stream>>>((const u32*)tm, flag);
  k_cvtw  <<<80, 256, 0, stream>>>(fc1w, xencw, wws);
  const int nrb = (N_NODES + G_BM - 1) / G_BM;    // 1563
  k_gemm1 <<<nrb, 256, 0, stream>>>(x, wws, fc1b, xencb, hws);
  k_rowhead<<<N_NODES / RH_BM, 128, 0, stream>>>(
      hws, y, tm, fc2w, fc2b, pw, flag, out + 2 * (size_t)E_NUM, sq, sk);
  k_edges <<<E_NUM / 256, 256, 0, stream>>>(ei, ein, sq, sk, pb, out);
}